// Round 22
// baseline (140.690 us; speedup 1.0000x reference)
//
#include <hip/hip_runtime.h>
#include <hip/hip_bf16.h>

// MultiHeadAttentionBlock: B=2, S=4096, D=512, H=8, DK=64.
// fp32 in/out, bf16 MFMA compute, fp32 accumulation.
// 4 dispatches: cvt_w (weights only); proj3 (Q/K/V GEMMs reading fp32 inputs
// DIRECTLY via reg-staged A: load f32->cvt->swizzled ds_write, B prefetched
// via global_load_lds; kills the 50MB X bf16 round-trip); flash attention
// (8-wave, 16q/wave, LDS K/V, swapped-operand, no-max exp2 softmax,
// in-register P via v_permlane32/16_swap, VGPR=40); out-proj GEMM.

typedef __bf16 bf16_t;
typedef __bf16 bf16x8 __attribute__((ext_vector_type(8)));
typedef __bf16 bf16x4 __attribute__((ext_vector_type(4)));
typedef __bf16 bf16x2 __attribute__((ext_vector_type(2)));
typedef float f32x4 __attribute__((ext_vector_type(4)));
typedef unsigned u32x4 __attribute__((ext_vector_type(4)));

#define S_LEN 4096
#define NH 8
#define DK 64
#define DMODEL 512
#define NB 2
#define KVB 64
#define QB 128

#define EXP2F(x) __builtin_amdgcn_exp2f(x)   // v_exp_f32 (2^x)

__device__ inline void gload_lds16(const void* g, void* l) {
  __builtin_amdgcn_global_load_lds(
      (const __attribute__((address_space(1))) unsigned int*)g,
      (__attribute__((address_space(3))) unsigned int*)l, 16, 0, 0);
}

__device__ inline unsigned pkbf(float a, float b) {
  bf16x2 t; t[0] = (__bf16)a; t[1] = (__bf16)b;
  return __builtin_bit_cast(unsigned, t);
}

__device__ inline bf16x8 cvt8(f32x4 lo, f32x4 hi) {
  bf16x8 r;
#pragma unroll
  for (int j = 0; j < 4; ++j) { r[j] = (__bf16)lo[j]; r[j + 4] = (__bf16)hi[j]; }
  return r;
}

// ---------------------------------------------------------------------------
// cvt_w: 4 weight matrices -> bf16, 8 elems/thread. Grid (128, 4).
// ---------------------------------------------------------------------------
__global__ __launch_bounds__(256) void cvt_w(
    const float* __restrict__ w0, const float* __restrict__ w1,
    const float* __restrict__ w2, const float* __restrict__ w3,
    bf16_t* __restrict__ o0, bf16_t* __restrict__ o1,
    bf16_t* __restrict__ o2, bf16_t* __restrict__ o3)
{
  const float* src = blockIdx.y == 0 ? w0 : blockIdx.y == 1 ? w1
                   : blockIdx.y == 2 ? w2 : w3;
  bf16_t* dst = blockIdx.y == 0 ? o0 : blockIdx.y == 1 ? o1
              : blockIdx.y == 2 ? o2 : o3;
  const int i = (blockIdx.x * 256 + threadIdx.x) * 8;
  f32x4 a = *reinterpret_cast<const f32x4*>(src + i);
  f32x4 b = *reinterpret_cast<const f32x4*>(src + i + 4);
  *reinterpret_cast<bf16x8*>(dst + i) = cvt8(a, b);
}

// ---------------------------------------------------------------------------
// Staged GEMM, 128x64 tile (BM=128, BN=64, BK=64), 4 waves, each 32(m)x64(n).
// TA=float (NF=3 proj): A reg-staged from fp32 with inline cvt; pipeline per
// K-step: WRITE_A(regs->buf) ; barrier ; issue LOAD_A(t+1) + gload_B(t+1) ;
// MFMA(buf). A-load latency hides under MFMA; B prefetch crosses the barrier.
// TA=bf16 (NF=1 out-proj): original all-gload_lds path.
// modes: 0 head-split [bh][s][dk]; 2 V^T [bh][dk][s]; 1 plain [m][n].
// ---------------------------------------------------------------------------
template <typename TA, typename TO, int NF>
__global__ __launch_bounds__(256) void gemm_tile(
    const TA* __restrict__ A0, const bf16_t* __restrict__ W0,
    const float* __restrict__ bb0, TO* __restrict__ oo0,
    const TA* __restrict__ A1, const bf16_t* __restrict__ W1,
    const float* __restrict__ bb1, TO* __restrict__ oo1,
    const TA* __restrict__ A2, const bf16_t* __restrict__ W2,
    const float* __restrict__ bb2, TO* __restrict__ oo2,
    int mode_last)
{
  const TA* A; const bf16_t* W; const float* bias; TO* out; int mode;
  if (NF == 3) {
    const int z = blockIdx.z;
    if (z == 0)      { A = A0; W = W0; bias = bb0; out = oo0; mode = 0; }
    else if (z == 1) { A = A1; W = W1; bias = bb1; out = oo1; mode = 0; }
    else             { A = A2; W = W2; bias = bb2; out = oo2; mode = 2; }
  } else { A = A0; W = W0; bias = bb0; out = oo0; mode = mode_last; }

  const int mtile = blockIdx.x * 128;
  const int ntile = blockIdx.y * 64;
  const int wave = threadIdx.x >> 6;
  const int lane = threadIdx.x & 63;
  const int l16 = lane & 15;
  const int g = lane >> 4;

  __shared__ bf16_t ldsA[2][128][64];  // 16 KB per buf
  __shared__ bf16_t ldsB[2][64][64];   // 8 KB per buf

  const int srow8 = 8 * wave + (lane >> 3);
  const int sslot = (lane & 7) ^ ((lane >> 3) & 7);
  const char* Bsrc = (const char*)W + ((size_t)(ntile + srow8) * DMODEL) * 2 + sslot * 16;
  const size_t rblk = (size_t)32 * DMODEL * 2;   // +32 rows (bytes, bf16)

  f32x4 acc[2][4];
#pragma unroll
  for (int mb = 0; mb < 2; ++mb)
#pragma unroll
    for (int nb = 0; nb < 4; ++nb) acc[mb][nb] = (f32x4){0.f, 0.f, 0.f, 0.f};

  const int rxor = (l16 & 7) << 4;
  const int NSTEP = DMODEL / 64;       // 8

#define GEMM_MFMA(BUFX)                                                       \
  {                                                                           \
    _Pragma("unroll")                                                         \
    for (int ks = 0; ks < 2; ++ks) {                                          \
      bf16x8 af[2];                                                           \
      _Pragma("unroll")                                                       \
      for (int mb = 0; mb < 2; ++mb) {                                        \
        const int arow = wave * 32 + mb * 16 + l16;                           \
        af[mb] = *reinterpret_cast<const bf16x8*>(                            \
            (const char*)&ldsA[BUFX][0][0] + arow * 128 +                     \
            ((ks * 64 + g * 16) ^ rxor));                                     \
      }                                                                       \
      _Pragma("unroll")                                                       \
      for (int nb = 0; nb < 4; ++nb) {                                        \
        const int brow = nb * 16 + l16;                                       \
        bf16x8 bfr = *reinterpret_cast<const bf16x8*>(                        \
            (const char*)&ldsB[BUFX][0][0] + brow * 128 +                     \
            ((ks * 64 + g * 16) ^ rxor));                                     \
        _Pragma("unroll")                                                     \
        for (int mb = 0; mb < 2; ++mb)                                        \
          acc[mb][nb] = __builtin_amdgcn_mfma_f32_16x16x32_bf16(              \
              af[mb], bfr, acc[mb][nb], 0, 0, 0);                             \
      }                                                                       \
    }                                                                         \
  }

  if constexpr (sizeof(TA) == 4) {
    // -------- fp32 A: reg-staged with inline cvt (4 units/thread) --------
    // unit u: idx = tid + 256u; row = idx>>3 (0..127), slot = idx&7 (16B slot)
    // LDS[row][slot] = A[row][slot ^ (row&7)]  (both-sides swizzle invariant)
    const float* abase[4];
    int wrow[4], wslot[4];
#pragma unroll
    for (int u = 0; u < 4; ++u) {
      const int idx = threadIdx.x + 256 * u;
      const int row = idx >> 3, slot = idx & 7;
      wrow[u] = row; wslot[u] = slot;
      const int sc = slot ^ (row & 7);
      abase[u] = (const float*)A + (size_t)(mtile + row) * DMODEL + sc * 8;
    }
    f32x4 ra[4][2];

#define LOAD_A(T)                                                             \
    _Pragma("unroll")                                                         \
    for (int u = 0; u < 4; ++u) {                                             \
      ra[u][0] = *reinterpret_cast<const f32x4*>(abase[u] + (T) * 64);        \
      ra[u][1] = *reinterpret_cast<const f32x4*>(abase[u] + (T) * 64 + 4);    \
    }
#define WRITE_A(BUFX)                                                         \
    _Pragma("unroll")                                                         \
    for (int u = 0; u < 4; ++u)                                               \
      *reinterpret_cast<bf16x8*>(&ldsA[BUFX][wrow[u]][wslot[u] * 8]) =        \
          cvt8(ra[u][0], ra[u][1]);

    LOAD_A(0);
#pragma unroll
    for (int c = 0; c < 2; ++c)
      gload_lds16(Bsrc + c * rblk, (char*)&ldsB[0][c * 32 + 8 * wave][0]);

    for (int t = 0; t < NSTEP; ++t) {
      const int buf = t & 1;
      WRITE_A(buf);                       // waits vmcnt on LOAD_A(t)
      __syncthreads();                    // drains gload_B(t); A writes visible
      if (t + 1 < NSTEP) {
        LOAD_A(t + 1);                    // in flight across MFMA
        const size_t ko = (size_t)(t + 1) * 128;
#pragma unroll
        for (int c = 0; c < 2; ++c)
          gload_lds16(Bsrc + c * rblk + ko,
                      (char*)&ldsB[buf ^ 1][c * 32 + 8 * wave][0]);
      }
      GEMM_MFMA(buf)
    }
#undef LOAD_A
#undef WRITE_A
  } else {
    // -------- bf16 A: original all-gload_lds path --------
    const char* Asrc = (const char*)A + ((size_t)(mtile + srow8) * DMODEL) * 2 + sslot * 16;
#pragma unroll
    for (int c = 0; c < 4; ++c)
      gload_lds16(Asrc + c * rblk, (char*)&ldsA[0][c * 32 + 8 * wave][0]);
#pragma unroll
    for (int c = 0; c < 2; ++c)
      gload_lds16(Bsrc + c * rblk, (char*)&ldsB[0][c * 32 + 8 * wave][0]);
    __syncthreads();

    int buf = 0;
    for (int t = 0; t < NSTEP; ++t) {
      if (t + 1 < NSTEP) {
        const size_t ko = (size_t)(t + 1) * 128;
#pragma unroll
        for (int c = 0; c < 4; ++c)
          gload_lds16(Asrc + c * rblk + ko, (char*)&ldsA[buf ^ 1][c * 32 + 8 * wave][0]);
#pragma unroll
        for (int c = 0; c < 2; ++c)
          gload_lds16(Bsrc + c * rblk + ko, (char*)&ldsB[buf ^ 1][c * 32 + 8 * wave][0]);
      }
      GEMM_MFMA(buf)
      __syncthreads();
      buf ^= 1;
    }
  }
#undef GEMM_MFMA

#pragma unroll
  for (int mb = 0; mb < 2; ++mb) {
    const int m0 = mtile + wave * 32 + mb * 16;
#pragma unroll
    for (int nb = 0; nb < 4; ++nb) {
      const int n = ntile + nb * 16 + l16;
      const float bv = bias[n];
#pragma unroll
      for (int r = 0; r < 4; ++r) {
        const int m = m0 + g * 4 + r;
        float vv = acc[mb][nb][r] + bv;
        size_t addr;
        if (mode == 0) {            // head-split [b*H+h][s][dk]
          int b = m >> 12, s = m & (S_LEN - 1);
          int h = n >> 6, d = n & 63;
          addr = (((size_t)(b * NH + h) * S_LEN) + s) * DK + d;
        } else if (mode == 2) {     // V transposed [b*H+h][dk][s]
          int b = m >> 12, s = m & (S_LEN - 1);
          int h = n >> 6, d = n & 63;
          addr = (((size_t)(b * NH + h) * DK) + d) * S_LEN + s;
        } else {                    // plain [m][n]
          addr = (size_t)m * DMODEL + n;
        }
        out[addr] = (TO)vv;
      }
    }
  }
}

// ---------------------------------------------------------------------------
// Flash attention (round-21 proven, 89us): 8-wave block, 16 q-rows/wave,
// LDS-staged K/V (dbuf, XOR swizzle), swapped-operand QK^T/PV, no-max exp2
// softmax, per-lane l, P redistributed in-register via v_permlane32/16_swap.
// ---------------------------------------------------------------------------
__global__ __launch_bounds__(512) void attn_kernel(
    const bf16_t* __restrict__ Qh, const bf16_t* __restrict__ Kh,
    const bf16_t* __restrict__ Vt, bf16_t* __restrict__ ctx)
{
  const int wg = blockIdx.x;
  const int bh = (wg & 7) * 2 + ((wg >> 3) & 1);
  const int qtile = wg >> 4;
  const int b = bh >> 3, h = bh & 7;
  const int wave = threadIdx.x >> 6;         // 0..7
  const int lane = threadIdx.x & 63;
  const int l16 = lane & 15;
  const int g = lane >> 4;                   // 0..3

  __shared__ bf16_t ldsK[2][KVB][64];
  __shared__ bf16_t ldsV[2][KVB][64];        // V^T tile: [d][kv]

  const bf16_t* Qp = Qh + (size_t)bh * S_LEN * DK;
  const bf16_t* Kp = Kh + (size_t)bh * S_LEN * DK;
  const bf16_t* Vp = Vt + (size_t)bh * DK * S_LEN;

  const int qrow0 = qtile * QB + wave * 16;

  const int srow = 8 * wave + (lane >> 3);
  const int scol16 = (lane & 7) ^ (lane >> 3);
  const char* Ksrc = (const char*)Kp + (size_t)srow * 128 + scol16 * 16;
  const char* Vsrc = (const char*)Vp + (size_t)srow * (S_LEN * 2) + scol16 * 16;

  const float qscale = 0.125f * 1.44269504089f;
  bf16x8 qf[2];
#pragma unroll
  for (int ks = 0; ks < 2; ++ks) {
    bf16x8 t = *reinterpret_cast<const bf16x8*>(
        Qp + (size_t)(qrow0 + l16) * DK + ks * 32 + g * 8);
#pragma unroll
    for (int j = 0; j < 8; ++j) t[j] = (__bf16)((float)t[j] * qscale);
    qf[ks] = t;
  }

  f32x4 o[4];
#pragma unroll
  for (int db = 0; db < 4; ++db) o[db] = (f32x4){0.f, 0.f, 0.f, 0.f};
  float l_run = 0.f;

  const int rxor = (l16 & 7) << 4;

  gload_lds16(Ksrc, (char*)&ldsK[0][8 * wave][0]);
  gload_lds16(Vsrc, (char*)&ldsV[0][8 * wave][0]);
  __syncthreads();

  const int NT = S_LEN / KVB;                // 64 (even)

#define TILE_BODY(BUF, T)                                                     \
  {                                                                           \
    const int tt = (T);                                                       \
    if (tt + 1 < NT) {                                                        \
      const size_t koff = (size_t)(tt + 1) * (KVB * 128);                     \
      const size_t voff = (size_t)(tt + 1) * (KVB * 2);                       \
      gload_lds16(Ksrc + koff, (char*)&ldsK[(BUF) ^ 1][8 * wave][0]);         \
      gload_lds16(Vsrc + voff, (char*)&ldsV[(BUF) ^ 1][8 * wave][0]);         \
    }                                                                         \
    f32x4 sc[4];                                                              \
    __builtin_amdgcn_s_setprio(1);                                            \
    _Pragma("unroll")                                                         \
    for (int nb = 0; nb < 4; ++nb) {                                          \
      f32x4 a = (f32x4){0.f, 0.f, 0.f, 0.f};                                  \
      _Pragma("unroll")                                                       \
      for (int ks = 0; ks < 2; ++ks) {                                        \
        const int row = nb * 16 + l16;                                        \
        bf16x8 kf = *reinterpret_cast<const bf16x8*>(                         \
            (const char*)&ldsK[BUF][0][0] + row * 128 +                       \
            ((ks * 64 + g * 16) ^ rxor));                                     \
        a = __builtin_amdgcn_mfma_f32_16x16x32_bf16(kf, qf[ks], a, 0, 0, 0);  \
      }                                                                       \
      sc[nb] = a;                                                             \
    }                                                                         \
    __builtin_amdgcn_s_setprio(0);                                            \
    unsigned Wp[4][2];                                                        \
    _Pragma("unroll")                                                         \
    for (int nb = 0; nb < 4; ++nb) {                                          \
      const float p0 = EXP2F(sc[nb][0]);                                      \
      const float p1 = EXP2F(sc[nb][1]);                                      \
      const float p2 = EXP2F(sc[nb][2]);                                      \
      const float p3 = EXP2F(sc[nb][3]);                                      \
      l_run += (p0 + p1) + (p2 + p3);                                         \
      Wp[nb][0] = pkbf(p0, p1);                                               \
      Wp[nb][1] = pkbf(p2, p3);                                               \
    }                                                                         \
    bf16x8 pf[2];                                                             \
    _Pragma("unroll")                                                         \
    for (int ks = 0; ks < 2; ++ks) {                                          \
      unsigned x0 = Wp[2 * ks][0], y0 = Wp[2 * ks + 1][0];                    \
      unsigned x1 = Wp[2 * ks][1], y1 = Wp[2 * ks + 1][1];                    \
      asm("v_permlane32_swap_b32 %0, %1" : "+v"(x0), "+v"(y0));               \
      asm("v_permlane16_swap_b32 %0, %1" : "+v"(x0), "+v"(y0));               \
      asm("v_permlane32_swap_b32 %0, %1" : "+v"(x1), "+v"(y1));               \
      asm("v_permlane16_swap_b32 %0, %1" : "+v"(x1), "+v"(y1));               \
      u32x4 pw4 = (u32x4){x0, x1, y0, y1};                                    \
      pf[ks] = __builtin_bit_cast(bf16x8, pw4);                               \
    }                                                                         \
    __builtin_amdgcn_s_setprio(1);                                            \
    _Pragma("unroll")                                                         \
    for (int ks = 0; ks < 2; ++ks) {                                          \
      _Pragma("unroll")                                                       \
      for (int db = 0; db < 4; ++db) {                                        \
        const int row = db * 16 + l16;                                        \
        bf16x8 vf = *reinterpret_cast<const bf16x8*>(                         \
            (const char*)&ldsV[BUF][0][0] + row * 128 +                       \
            ((ks * 64 + g * 16) ^ rxor));                                     \
        o[db] = __builtin_amdgcn_mfma_f32_16x16x32_bf16(vf, pf[ks], o[db], 0, 0, 0); \
      }                                                                       \
    }                                                                         \
    __builtin_amdgcn_s_setprio(0);                                            \
    __syncthreads();                                                          \
  }

  for (int t = 0; t < NT; t += 2) {
    TILE_BODY(0, t)
    TILE_BODY(1, t + 1)
  }
#undef TILE_BODY

  float l_row = l_run;
  l_row += __shfl_xor(l_row, 16);
  l_row += __shfl_xor(l_row, 32);
  const float inv_l = 1.f / l_row;
  bf16_t* crow = ctx + (((size_t)(b * S_LEN + qrow0 + l16)) * NH + h) * DK;
#pragma unroll
  for (int db = 0; db < 4; ++db) {
    bf16x4 cw;
#pragma unroll
    for (int r = 0; r < 4; ++r) cw[r] = (__bf16)(o[db][r] * inv_l);
    *reinterpret_cast<bf16x4*>(crow + db * 16 + g * 4) = cw;
  }
}

// ---------------------------------------------------------------------------
extern "C" void kernel_launch(void* const* d_in, const int* in_sizes, int n_in,
                              void* d_out, int out_size, void* d_ws, size_t ws_size,
                              hipStream_t stream)
{
  const float* q   = (const float*)d_in[0];
  const float* k   = (const float*)d_in[1];
  const float* v   = (const float*)d_in[2];
  const float* w_q = (const float*)d_in[3];
  const float* b_q = (const float*)d_in[4];
  const float* w_k = (const float*)d_in[5];
  const float* b_k = (const float*)d_in[6];
  const float* w_v = (const float*)d_in[7];
  const float* b_v = (const float*)d_in[8];
  const float* w_o = (const float*)d_in[9];
  const float* b_o = (const float*)d_in[10];
  float* out = (float*)d_out;

  char* ws = (char*)d_ws;
  const size_t sz = (size_t)NB * NH * S_LEN * DK * sizeof(bf16_t);  // 8 MiB
  const size_t wsz = (size_t)DMODEL * DMODEL * sizeof(bf16_t);      // 512 KiB
  // slots: s0=ctx; s1=Qh; s2=Kh; s3=Vt; weights after.
  bf16_t* ctx = (bf16_t*)(ws);
  bf16_t* Qh  = (bf16_t*)(ws + sz);
  bf16_t* Kh  = (bf16_t*)(ws + 2 * sz);
  bf16_t* Vt  = (bf16_t*)(ws + 3 * sz);
  bf16_t* Wq  = (bf16_t*)(ws + 4 * sz);
  bf16_t* Wk  = (bf16_t*)(ws + 4 * sz + wsz);
  bf16_t* Wv  = (bf16_t*)(ws + 4 * sz + 2 * wsz);
  bf16_t* Wo  = (bf16_t*)(ws + 4 * sz + 3 * wsz);

  // 1) weight conversion only (inputs consumed fp32 directly by proj3)
  cvt_w<<<dim3(128, 4), 256, 0, stream>>>(w_q, w_k, w_v, w_o, Wq, Wk, Wv, Wo);

  dim3 bb(256);
  // 2) all three projections in one launch, fp32 A reg-staged
  gemm_tile<float, bf16_t, 3><<<dim3(64, 8, 3), bb, 0, stream>>>(
      q, Wq, b_q, Qh, k, Wk, b_k, Kh, v, Wv, b_v, Vt, 0);

  // 3) attention
  attn_kernel<<<dim3(512), dim3(512), 0, stream>>>(Qh, Kh, Vt, ctx);

  // 4) output projection, fp32 out
  gemm_tile<bf16_t, float, 1><<<dim3(64, 8), bb, 0, stream>>>(
      ctx, Wo, b_o, out, nullptr, nullptr, nullptr, nullptr,
      nullptr, nullptr, nullptr, nullptr, 1);
}

// Round 23
// 137.884 us; speedup vs baseline: 1.0203x; 1.0203x over previous
//
#include <hip/hip_runtime.h>
#include <hip/hip_bf16.h>

// MultiHeadAttentionBlock: B=2, S=4096, D=512, H=8, DK=64.
// fp32 in/out, bf16 MFMA compute, fp32 accumulation. SESSION-BEST (138us):
// 4 dispatches: cvt_all; proj3 (Q/K/V GEMMs in one launch, 128x64 tiles,
// global_load_lds dbuf, XOR swizzle); flash attention (8-wave, 16q/wave,
// LDS-staged K/V, swapped-operand, no-max exp2 softmax, in-register P via
// v_permlane32/16_swap, VGPR=40, LDS 32KB); out-proj GEMM.

typedef __bf16 bf16_t;
typedef __bf16 bf16x8 __attribute__((ext_vector_type(8)));
typedef __bf16 bf16x4 __attribute__((ext_vector_type(4)));
typedef __bf16 bf16x2 __attribute__((ext_vector_type(2)));
typedef float f32x4 __attribute__((ext_vector_type(4)));
typedef unsigned u32x4 __attribute__((ext_vector_type(4)));

#define S_LEN 4096
#define NH 8
#define DK 64
#define DMODEL 512
#define NB 2
#define KVB 64
#define QB 128

#define EXP2F(x) __builtin_amdgcn_exp2f(x)   // v_exp_f32 (2^x)

__device__ inline void gload_lds16(const void* g, void* l) {
  __builtin_amdgcn_global_load_lds(
      (const __attribute__((address_space(1))) unsigned int*)g,
      (__attribute__((address_space(3))) unsigned int*)l, 16, 0, 0);
}

// pack two f32 -> one u32 of 2 bf16
__device__ inline unsigned pkbf(float a, float b) {
  bf16x2 t; t[0] = (__bf16)a; t[1] = (__bf16)b;
  return __builtin_bit_cast(unsigned, t);
}

// ---------------------------------------------------------------------------
// cvt_all: q,k,v (2048 blocks each) + 4 weight matrices (128 blocks each)
// -> bf16, 8 elems/thread, one launch. Grid 6656.
// ---------------------------------------------------------------------------
__global__ __launch_bounds__(256) void cvt_all(
    const float* __restrict__ q, const float* __restrict__ k,
    const float* __restrict__ v, const float* __restrict__ w0,
    const float* __restrict__ w1, const float* __restrict__ w2,
    const float* __restrict__ w3, bf16_t* __restrict__ x0,
    bf16_t* __restrict__ x1, bf16_t* __restrict__ x2,
    bf16_t* __restrict__ o0, bf16_t* __restrict__ o1,
    bf16_t* __restrict__ o2, bf16_t* __restrict__ o3)
{
  const int bid = blockIdx.x;
  const float* src; bf16_t* dst; int i;
  if (bid < 6144) {
    const int z = bid >> 11;                 // 0..2
    src = z == 0 ? q : z == 1 ? k : v;
    dst = z == 0 ? x0 : z == 1 ? x1 : x2;
    i = ((bid & 2047) * 256 + threadIdx.x) * 8;
  } else {
    const int w = (bid - 6144) >> 7;         // 0..3
    src = w == 0 ? w0 : w == 1 ? w1 : w == 2 ? w2 : w3;
    dst = w == 0 ? o0 : w == 1 ? o1 : w == 2 ? o2 : o3;
    i = (((bid - 6144) & 127) * 256 + threadIdx.x) * 8;
  }
  f32x4 a = *reinterpret_cast<const f32x4*>(src + i);
  f32x4 b = *reinterpret_cast<const f32x4*>(src + i + 4);
  bf16x8 r;
#pragma unroll
  for (int j = 0; j < 4; ++j) { r[j] = (__bf16)a[j]; r[j + 4] = (__bf16)b[j]; }
  *reinterpret_cast<bf16x8*>(dst + i) = r;
}

// ---------------------------------------------------------------------------
// Staged GEMM, 128x64 tile (BM=128, BN=64, BK=64), 4 waves, each 32(m)x64(n).
// NF=3: blockIdx.z selects (Q proj mode0 / K proj mode0 / V proj mode2).
// NF=1: single GEMM with mode_last.
// modes: 0 head-split [bh][s][dk]; 2 V^T [bh][dk][s]; 1 plain [m][n].
// ---------------------------------------------------------------------------
template <typename TO, int NF>
__global__ __launch_bounds__(256) void gemm_tile(
    const bf16_t* __restrict__ A0, const bf16_t* __restrict__ W0,
    const float* __restrict__ bb0, TO* __restrict__ oo0,
    const bf16_t* __restrict__ A1, const bf16_t* __restrict__ W1,
    const float* __restrict__ bb1, TO* __restrict__ oo1,
    const bf16_t* __restrict__ A2, const bf16_t* __restrict__ W2,
    const float* __restrict__ bb2, TO* __restrict__ oo2,
    int mode_last)
{
  const bf16_t* A; const bf16_t* W; const float* bias; TO* out; int mode;
  if (NF == 3) {
    const int z = blockIdx.z;
    if (z == 0)      { A = A0; W = W0; bias = bb0; out = oo0; mode = 0; }
    else if (z == 1) { A = A1; W = W1; bias = bb1; out = oo1; mode = 0; }
    else             { A = A2; W = W2; bias = bb2; out = oo2; mode = 2; }
  } else { A = A0; W = W0; bias = bb0; out = oo0; mode = mode_last; }

  const int mtile = blockIdx.x * 128;
  const int ntile = blockIdx.y * 64;
  const int wave = threadIdx.x >> 6;
  const int lane = threadIdx.x & 63;
  const int l16 = lane & 15;
  const int g = lane >> 4;

  __shared__ bf16_t ldsA[2][128][64];  // 16 KB per buf
  __shared__ bf16_t ldsB[2][64][64];   // 8 KB per buf

  const int srow8 = 8 * wave + (lane >> 3);
  const int sslot = (lane & 7) ^ ((lane >> 3) & 7);
  const char* Asrc = (const char*)A + ((size_t)(mtile + srow8) * DMODEL) * 2 + sslot * 16;
  const char* Bsrc = (const char*)W + ((size_t)(ntile + srow8) * DMODEL) * 2 + sslot * 16;
  const size_t rblk = (size_t)32 * DMODEL * 2;   // +32 rows

  f32x4 acc[2][4];
#pragma unroll
  for (int mb = 0; mb < 2; ++mb)
#pragma unroll
    for (int nb = 0; nb < 4; ++nb) acc[mb][nb] = (f32x4){0.f, 0.f, 0.f, 0.f};

  const int rxor = (l16 & 7) << 4;

#pragma unroll
  for (int c = 0; c < 4; ++c)
    gload_lds16(Asrc + c * rblk, (char*)&ldsA[0][c * 32 + 8 * wave][0]);
#pragma unroll
  for (int c = 0; c < 2; ++c)
    gload_lds16(Bsrc + c * rblk, (char*)&ldsB[0][c * 32 + 8 * wave][0]);
  __syncthreads();

  const int NSTEP = DMODEL / 64;       // 8
  int buf = 0;
  for (int t = 0; t < NSTEP; ++t) {
    if (t + 1 < NSTEP) {
      const size_t ko = (size_t)(t + 1) * 128;
#pragma unroll
      for (int c = 0; c < 4; ++c)
        gload_lds16(Asrc + c * rblk + ko, (char*)&ldsA[buf ^ 1][c * 32 + 8 * wave][0]);
#pragma unroll
      for (int c = 0; c < 2; ++c)
        gload_lds16(Bsrc + c * rblk + ko, (char*)&ldsB[buf ^ 1][c * 32 + 8 * wave][0]);
    }

#pragma unroll
    for (int ks = 0; ks < 2; ++ks) {
      bf16x8 af[2];
#pragma unroll
      for (int mb = 0; mb < 2; ++mb) {
        const int arow = wave * 32 + mb * 16 + l16;
        af[mb] = *reinterpret_cast<const bf16x8*>(
            (const char*)&ldsA[buf][0][0] + arow * 128 + ((ks * 64 + g * 16) ^ rxor));
      }
#pragma unroll
      for (int nb = 0; nb < 4; ++nb) {
        const int brow = nb * 16 + l16;
        bf16x8 bfr = *reinterpret_cast<const bf16x8*>(
            (const char*)&ldsB[buf][0][0] + brow * 128 + ((ks * 64 + g * 16) ^ rxor));
#pragma unroll
        for (int mb = 0; mb < 2; ++mb)
          acc[mb][nb] = __builtin_amdgcn_mfma_f32_16x16x32_bf16(af[mb], bfr, acc[mb][nb], 0, 0, 0);
      }
    }

    __syncthreads();
    buf ^= 1;
  }

#pragma unroll
  for (int mb = 0; mb < 2; ++mb) {
    const int m0 = mtile + wave * 32 + mb * 16;
#pragma unroll
    for (int nb = 0; nb < 4; ++nb) {
      const int n = ntile + nb * 16 + l16;
      const float bv = bias[n];
#pragma unroll
      for (int r = 0; r < 4; ++r) {
        const int m = m0 + g * 4 + r;
        float vv = acc[mb][nb][r] + bv;
        size_t addr;
        if (mode == 0) {            // head-split [b*H+h][s][dk]
          int b = m >> 12, s = m & (S_LEN - 1);
          int h = n >> 6, d = n & 63;
          addr = (((size_t)(b * NH + h) * S_LEN) + s) * DK + d;
        } else if (mode == 2) {     // V transposed [b*H+h][dk][s]
          int b = m >> 12, s = m & (S_LEN - 1);
          int h = n >> 6, d = n & 63;
          addr = (((size_t)(b * NH + h) * DK) + d) * S_LEN + s;
        } else {                    // plain [m][n]
          addr = (size_t)m * DMODEL + n;
        }
        out[addr] = (TO)vv;
      }
    }
  }
}

// ---------------------------------------------------------------------------
// Flash attention (proven 89us): 8-wave block, 16 q-rows/wave, LDS-staged K/V
// (dbuf, XOR swizzle), swapped-operand QK^T/PV, no-max exp2 softmax (scores
// in log2 units, range ~±10 << fp32 exp range), per-lane l partials, P
// redistributed in-register via v_permlane32/16_swap (no LDS round-trip).
// ---------------------------------------------------------------------------
__global__ __launch_bounds__(512) void attn_kernel(
    const bf16_t* __restrict__ Qh, const bf16_t* __restrict__ Kh,
    const bf16_t* __restrict__ Vt, bf16_t* __restrict__ ctx)
{
  const int wg = blockIdx.x;
  const int bh = (wg & 7) * 2 + ((wg >> 3) & 1);
  const int qtile = wg >> 4;
  const int b = bh >> 3, h = bh & 7;
  const int wave = threadIdx.x >> 6;         // 0..7
  const int lane = threadIdx.x & 63;
  const int l16 = lane & 15;
  const int g = lane >> 4;                   // 0..3

  __shared__ bf16_t ldsK[2][KVB][64];
  __shared__ bf16_t ldsV[2][KVB][64];        // V^T tile: [d][kv]

  const bf16_t* Qp = Qh + (size_t)bh * S_LEN * DK;
  const bf16_t* Kp = Kh + (size_t)bh * S_LEN * DK;
  const bf16_t* Vp = Vt + (size_t)bh * DK * S_LEN;

  const int qrow0 = qtile * QB + wave * 16;

  const int srow = 8 * wave + (lane >> 3);
  const int scol16 = (lane & 7) ^ (lane >> 3);
  const char* Ksrc = (const char*)Kp + (size_t)srow * 128 + scol16 * 16;
  const char* Vsrc = (const char*)Vp + (size_t)srow * (S_LEN * 2) + scol16 * 16;

  // Q fragment, pre-scaled by (1/sqrt(DK)) * log2(e) -> scores in log2 units
  const float qscale = 0.125f * 1.44269504089f;
  bf16x8 qf[2];
#pragma unroll
  for (int ks = 0; ks < 2; ++ks) {
    bf16x8 t = *reinterpret_cast<const bf16x8*>(
        Qp + (size_t)(qrow0 + l16) * DK + ks * 32 + g * 8);
#pragma unroll
    for (int j = 0; j < 8; ++j) t[j] = (__bf16)((float)t[j] * qscale);
    qf[ks] = t;
  }

  f32x4 o[4];
#pragma unroll
  for (int db = 0; db < 4; ++db) o[db] = (f32x4){0.f, 0.f, 0.f, 0.f};
  float l_run = 0.f;                         // PER-LANE partial (reduced at end)

  const int rxor = (l16 & 7) << 4;

  gload_lds16(Ksrc, (char*)&ldsK[0][8 * wave][0]);
  gload_lds16(Vsrc, (char*)&ldsV[0][8 * wave][0]);
  __syncthreads();

  const int NT = S_LEN / KVB;                // 64 (even)

#define TILE_BODY(BUF, T)                                                     \
  {                                                                           \
    const int tt = (T);                                                       \
    if (tt + 1 < NT) {                                                        \
      const size_t koff = (size_t)(tt + 1) * (KVB * 128);                     \
      const size_t voff = (size_t)(tt + 1) * (KVB * 2);                       \
      gload_lds16(Ksrc + koff, (char*)&ldsK[(BUF) ^ 1][8 * wave][0]);         \
      gload_lds16(Vsrc + voff, (char*)&ldsV[(BUF) ^ 1][8 * wave][0]);         \
    }                                                                         \
    f32x4 sc[4];                                                              \
    __builtin_amdgcn_s_setprio(1);                                            \
    _Pragma("unroll")                                                         \
    for (int nb = 0; nb < 4; ++nb) {                                          \
      f32x4 a = (f32x4){0.f, 0.f, 0.f, 0.f};                                  \
      _Pragma("unroll")                                                       \
      for (int ks = 0; ks < 2; ++ks) {                                        \
        const int row = nb * 16 + l16;                                        \
        bf16x8 kf = *reinterpret_cast<const bf16x8*>(                         \
            (const char*)&ldsK[BUF][0][0] + row * 128 +                       \
            ((ks * 64 + g * 16) ^ rxor));                                     \
        a = __builtin_amdgcn_mfma_f32_16x16x32_bf16(kf, qf[ks], a, 0, 0, 0);  \
      }                                                                       \
      sc[nb] = a;                                                             \
    }                                                                         \
    __builtin_amdgcn_s_setprio(0);                                            \
    unsigned Wp[4][2];                                                        \
    _Pragma("unroll")                                                         \
    for (int nb = 0; nb < 4; ++nb) {                                          \
      const float p0 = EXP2F(sc[nb][0]);                                      \
      const float p1 = EXP2F(sc[nb][1]);                                      \
      const float p2 = EXP2F(sc[nb][2]);                                      \
      const float p3 = EXP2F(sc[nb][3]);                                      \
      l_run += (p0 + p1) + (p2 + p3);                                         \
      Wp[nb][0] = pkbf(p0, p1);                                               \
      Wp[nb][1] = pkbf(p2, p3);                                               \
    }                                                                         \
    bf16x8 pf[2];                                                             \
    _Pragma("unroll")                                                         \
    for (int ks = 0; ks < 2; ++ks) {                                          \
      unsigned x0 = Wp[2 * ks][0], y0 = Wp[2 * ks + 1][0];                    \
      unsigned x1 = Wp[2 * ks][1], y1 = Wp[2 * ks + 1][1];                    \
      asm("v_permlane32_swap_b32 %0, %1" : "+v"(x0), "+v"(y0));               \
      asm("v_permlane16_swap_b32 %0, %1" : "+v"(x0), "+v"(y0));               \
      asm("v_permlane32_swap_b32 %0, %1" : "+v"(x1), "+v"(y1));               \
      asm("v_permlane16_swap_b32 %0, %1" : "+v"(x1), "+v"(y1));               \
      u32x4 pw4 = (u32x4){x0, x1, y0, y1};                                    \
      pf[ks] = __builtin_bit_cast(bf16x8, pw4);                               \
    }                                                                         \
    __builtin_amdgcn_s_setprio(1);                                            \
    _Pragma("unroll")                                                         \
    for (int ks = 0; ks < 2; ++ks) {                                          \
      _Pragma("unroll")                                                       \
      for (int db = 0; db < 4; ++db) {                                        \
        const int row = db * 16 + l16;                                        \
        bf16x8 vf = *reinterpret_cast<const bf16x8*>(                         \
            (const char*)&ldsV[BUF][0][0] + row * 128 +                       \
            ((ks * 64 + g * 16) ^ rxor));                                     \
        o[db] = __builtin_amdgcn_mfma_f32_16x16x32_bf16(vf, pf[ks], o[db], 0, 0, 0); \
      }                                                                       \
    }                                                                         \
    __builtin_amdgcn_s_setprio(0);                                            \
    __syncthreads();                                                          \
  }

  for (int t = 0; t < NT; t += 2) {
    TILE_BODY(0, t)
    TILE_BODY(1, t + 1)
  }
#undef TILE_BODY

  // ---- epilogue: row-sum of per-lane l partials (once), normalize, store ---
  float l_row = l_run;
  l_row += __shfl_xor(l_row, 16);
  l_row += __shfl_xor(l_row, 32);
  const float inv_l = 1.f / l_row;
  bf16_t* crow = ctx + (((size_t)(b * S_LEN + qrow0 + l16)) * NH + h) * DK;
#pragma unroll
  for (int db = 0; db < 4; ++db) {
    bf16x4 cw;
#pragma unroll
    for (int r = 0; r < 4; ++r) cw[r] = (__bf16)(o[db][r] * inv_l);
    *reinterpret_cast<bf16x4*>(crow + db * 16 + g * 4) = cw;
  }
}

// ---------------------------------------------------------------------------
extern "C" void kernel_launch(void* const* d_in, const int* in_sizes, int n_in,
                              void* d_out, int out_size, void* d_ws, size_t ws_size,
                              hipStream_t stream)
{
  const float* q   = (const float*)d_in[0];
  const float* k   = (const float*)d_in[1];
  const float* v   = (const float*)d_in[2];
  const float* w_q = (const float*)d_in[3];
  const float* b_q = (const float*)d_in[4];
  const float* w_k = (const float*)d_in[5];
  const float* b_k = (const float*)d_in[6];
  const float* w_v = (const float*)d_in[7];
  const float* b_v = (const float*)d_in[8];
  const float* w_o = (const float*)d_in[9];
  const float* b_o = (const float*)d_in[10];
  float* out = (float*)d_out;

  char* ws = (char*)d_ws;
  const size_t sz = (size_t)NB * NH * S_LEN * DK * sizeof(bf16_t);  // 8 MiB
  const size_t wsz = (size_t)DMODEL * DMODEL * sizeof(bf16_t);      // 512 KiB
  // slots: s0=Xq->Vt; s1=Xk->ctx; s2=Xv; s3=Qh; s4=Kh; weights after.
  bf16_t* X0 = (bf16_t*)(ws);
  bf16_t* X1 = (bf16_t*)(ws + sz);
  bf16_t* X2 = (bf16_t*)(ws + 2 * sz);
  bf16_t* Qh = (bf16_t*)(ws + 3 * sz);
  bf16_t* Kh = (bf16_t*)(ws + 4 * sz);
  bf16_t* Wq = (bf16_t*)(ws + 5 * sz);
  bf16_t* Wk = (bf16_t*)(ws + 5 * sz + wsz);
  bf16_t* Wv = (bf16_t*)(ws + 5 * sz + 2 * wsz);
  bf16_t* Wo = (bf16_t*)(ws + 5 * sz + 3 * wsz);
  bf16_t* Vt  = X0;   // reuses Xq slot (free after proj3)
  bf16_t* ctx = X1;   // reuses Xk slot (free after proj3)

  // 1) all conversions in one launch
  cvt_all<<<dim3(6656), 256, 0, stream>>>(q, k, v, w_q, w_k, w_v, w_o,
                                          X0, X1, X2, Wq, Wk, Wv, Wo);

  dim3 bb(256);
  // 2) all three projections in one launch (z: Q mode0, K mode0, V mode2)
  gemm_tile<bf16_t, 3><<<dim3(64, 8, 3), bb, 0, stream>>>(
      X0, Wq, b_q, Qh, X1, Wk, b_k, Kh, X2, Wv, b_v, Vt, 0);

  // 3) attention
  attn_kernel<<<dim3(512), dim3(512), 0, stream>>>(Qh, Kh, Vt, ctx);

  // 4) output projection, fp32 out
  gemm_tile<float, 1><<<dim3(64, 8), bb, 0, stream>>>(
      ctx, Wo, b_o, out, nullptr, nullptr, nullptr, nullptr,
      nullptr, nullptr, nullptr, nullptr, 1);
}